// Round 5
// baseline (269.944 us; speedup 1.0000x reference)
//
#include <hip/hip_runtime.h>
#include <hip/hip_bf16.h>
#include <cstddef>

#define T_DIM 2048
#define B_DIM 64
#define I_DIM 128
#define H_DIM 128
#define FC_DIM 32
#define O_DIM 2

#define NC 32                // time chunks (parallel affine scan)
#define TC (T_DIM / NC)      // 64 timesteps per chunk
#define MT 4                 // 4 m-tiles of 16 t per chunk
#define SUBT (TC / 4)        // 16 timesteps per quad sub-chunk

#define LOG2E  1.44269504088896f
#define LOG2E2 2.88539008177793f

typedef __attribute__((ext_vector_type(8))) short bf16x8;
typedef __attribute__((ext_vector_type(4))) float f32x4;

// packed fp32x8 -> bf16x8 (RNE) via v_cvt_pk_bf16_f32
__device__ __forceinline__ bf16x8 cvt8(const float* __restrict__ p) {
    union { bf16x8 v; __hip_bfloat162 h2[4]; } u;
#pragma unroll
    for (int j = 0; j < 4; ++j) {
        float2 f2 = {p[2 * j], p[2 * j + 1]};
        u.h2[j] = __float22bfloat162_rn(f2);
    }
    return u.v;
}

// Pass 0: gate weights fp32 -> bf16, pre-scaled by log2e factors so the
// gates kernel can use exp2 directly. Layout preserved [b][h][i].
__global__ void convert_w_kernel(const float* __restrict__ wg,
                                 const float* __restrict__ wi,
                                 const float* __restrict__ wf,
                                 short* __restrict__ og,
                                 short* __restrict__ oi,
                                 short* __restrict__ of)
{
    const float* src = (blockIdx.y == 0) ? wg : (blockIdx.y == 1) ? wi : wf;
    short* dst       = (blockIdx.y == 0) ? og : (blockIdx.y == 1) ? oi : of;
    const float scale = (blockIdx.y == 0) ? LOG2E2 : LOG2E;
    const size_t idx = ((size_t)blockIdx.x * 256 + threadIdx.x) * 8;
    float4 u0 = *(const float4*)(src + idx);
    float4 u1 = *(const float4*)(src + idx + 4);
    float a[8] = {u0.x * scale, u0.y * scale, u0.z * scale, u0.w * scale,
                  u1.x * scale, u1.y * scale, u1.z * scale, u1.w * scale};
    *(bf16x8*)(dst + idx) = cvt8(a);
}

// Pass 1: one block per (b, chunk), 8 waves covering all 128 h.
// Phase A: 2 waves per m-tile convert the chunk's x slice (fp32, read once)
//          into bf16 MFMA A-fragments in LDS (fragment-order layout ->
//          conflict-free b128 writes & reads).
// Phase B: per m-tile: 4 ds_read_b128, 12 MFMA, exp2-based activations,
//          per-quad affine scan; cross-quad combine at end.
// m-row -> t map within chunk: t(m) = (m>>2)*SUBT + mt*4 + (m&3); D rows
// (row = quad*4 + r) give each quad 4 consecutive t; quad q owns
// [q*SUBT, (q+1)*SUBT).
__global__ __launch_bounds__(512, 8)
void gates_scan_kernel(const float* __restrict__ x,
    const short* __restrict__ wg, const short* __restrict__ wi,
    const short* __restrict__ wf,
    const float* __restrict__ b_g, const float* __restrict__ b_i,
    const float* __restrict__ b_f,
    float* __restrict__ wsF, float* __restrict__ wsA)
{
    // frag[mt][kk][lane][8 shorts] = 4*4*64*8 shorts = 16 KB
    __shared__ short frag[MT * 4 * 64 * 8];

    const int L    = threadIdx.x & 63;
    const int wv   = threadIdx.x >> 6;   // 0..7
    const int col  = L & 15;
    const int quad = L >> 4;
    const int bid  = blockIdx.x;
    const int b     = bid & (B_DIM - 1);  // b-minor: same-b blocks 64 apart -> same XCD
    const int chunk = bid >> 6;

    // ---- weight fragments for this wave's 16 h columns: h = wv*16 + col
    const int h = wv * 16 + col;
    bf16x8 Bg[4], Bi[4], Bf[4];
    {
        const size_t wo = ((size_t)b * H_DIM + h) * I_DIM + quad * 8;
#pragma unroll
        for (int kk = 0; kk < 4; ++kk) {
            Bg[kk] = *(const bf16x8*)(wg + wo + kk * 32);
            Bi[kk] = *(const bf16x8*)(wi + wo + kk * 32);
            Bf[kk] = *(const bf16x8*)(wf + wo + kk * 32);
        }
    }
    const float biasg = b_g[b * H_DIM + h] * LOG2E2;
    const float biasi = b_i[b * H_DIM + h] * LOG2E;
    const float biasf = b_f[b * H_DIM + h] * LOG2E;

    // ---- Phase A: 2 waves per m-tile (each wave converts 2 k-slices)
    {
        const int mt = wv & 3;
        const int k0 = (wv >> 2) * 2;
        const int tl = (col >> 2) * SUBT + mt * 4 + (col & 3);  // t within chunk
        const float* xp = x + ((size_t)(chunk * TC + tl) * B_DIM + b) * I_DIM;
#pragma unroll
        for (int kx = 0; kx < 2; ++kx) {
            const int kk = k0 + kx;
            const int i0 = quad * 8 + kk * 32;
            float4 u0 = *(const float4*)(xp + i0);
            float4 u1 = *(const float4*)(xp + i0 + 4);
            float a[8] = {u0.x, u0.y, u0.z, u0.w, u1.x, u1.y, u1.z, u1.w};
            *(bf16x8*)(frag + (((mt * 4 + kk) * 64) + L) * 8) = cvt8(a);
        }
    }
    __syncthreads();

    // ---- Phase B: MFMA + activations + per-quad scan
    float Fq = 1.0f, Aq = 0.0f;
#pragma unroll
    for (int mt = 0; mt < MT; ++mt) {
        bf16x8 ah[4];
#pragma unroll
        for (int kk = 0; kk < 4; ++kk)
            ah[kk] = *(const bf16x8*)(frag + (((mt * 4 + kk) * 64) + L) * 8);
        f32x4 accg = {0.f, 0.f, 0.f, 0.f};
        f32x4 acci = {0.f, 0.f, 0.f, 0.f};
        f32x4 accf = {0.f, 0.f, 0.f, 0.f};
#pragma unroll
        for (int kk = 0; kk < 4; ++kk) {
            accg = __builtin_amdgcn_mfma_f32_16x16x32_bf16(ah[kk], Bg[kk], accg, 0, 0, 0);
            acci = __builtin_amdgcn_mfma_f32_16x16x32_bf16(ah[kk], Bi[kk], acci, 0, 0, 0);
            accf = __builtin_amdgcn_mfma_f32_16x16x32_bf16(ah[kk], Bf[kk], accf, 0, 0, 0);
        }
        // D row = quad*4 + r -> t = quad*SUBT + mt*4 + r (consecutive per quad)
#pragma unroll
        for (int r = 0; r < 4; ++r) {
            // preacts pre-scaled by log2e (g by 2*log2e): use exp2 directly
            float g  = 2.0f * __builtin_amdgcn_rcpf(
                           1.0f + __builtin_amdgcn_exp2f(-(accg[r] + biasg))) - 1.0f;
            float iv = __builtin_amdgcn_rcpf(
                           1.0f + __builtin_amdgcn_exp2f(-(acci[r] + biasi)));
            float fv = __builtin_amdgcn_rcpf(
                           1.0f + __builtin_amdgcn_exp2f(-(accf[r] + biasf)));
            Aq = fv * Aq + iv * g;
            Fq = fv * Fq;
        }
    }

    // Ordered cross-quad combine (quad q covers t-range q*SUBT..): 2 rounds.
    float Fo = __shfl_xor(Fq, 16, 64);
    float Ao = __shfl_xor(Aq, 16, 64);
    if ((quad & 1) == 0) { Aq = Fo * Aq + Ao; Fq = Fo * Fq; }
    else                 { Aq = Fq * Ao + Aq; Fq = Fq * Fo; }
    Fo = __shfl_xor(Fq, 32, 64);
    Ao = __shfl_xor(Aq, 32, 64);
    if (quad < 2) { Aq = Fo * Aq + Ao; Fq = Fo * Fq; }
    else          { Aq = Fq * Ao + Aq; Fq = Fq * Fo; }

    if (quad == 0) {
        const int idx = (b * NC + chunk) * H_DIM + h;
        wsF[idx] = Fq;
        wsA[idx] = Aq;
    }
}

// Pass 2: fold NC chunk-affines -> c_fin; o-gate at t=T-1 (fp32 dot);
// h_fin = o*tanh(c); classifier + log_softmax. One block per batch.
__global__ void finish_kernel(const float* __restrict__ x,
    const float* __restrict__ w_io, const float* __restrict__ b_o,
    const float* __restrict__ fc1_w, const float* __restrict__ fc1_b,
    const float* __restrict__ fc2_w, const float* __restrict__ fc2_b,
    const float* __restrict__ wsF, const float* __restrict__ wsA,
    float* __restrict__ out)
{
    const int b = blockIdx.x;
    const int h = threadIdx.x;  // 128 threads
    __shared__ float hf[H_DIM];
    __shared__ float z1[FC_DIM];

    float c = 0.0f;
#pragma unroll
    for (int nc = 0; nc < NC; ++nc) {
        const int idx = (b * NC + nc) * H_DIM + h;
        c = wsF[idx] * c + wsA[idx];
    }
    const float* xl = x + ((size_t)(T_DIM - 1) * B_DIM + b) * I_DIM;
    const float* wo = w_io + ((size_t)b * H_DIM + h) * I_DIM;
    float acc = b_o[b * H_DIM + h];
#pragma unroll 8
    for (int i = 0; i < I_DIM; i += 4) {
        float4 xa = *(const float4*)(xl + i);
        float4 wa = *(const float4*)(wo + i);
        acc += xa.x * wa.x + xa.y * wa.y + xa.z * wa.z + xa.w * wa.w;
    }
    const float o = 1.0f / (1.0f + expf(-acc));
    hf[h] = o * tanhf(c);
    __syncthreads();

    if (h < FC_DIM) {
        float a = fc1_b[h];
        const float* w1 = fc1_w + h * H_DIM;
        for (int i = 0; i < H_DIM; ++i) a += w1[i] * hf[i];
        z1[h] = tanhf(a);
    }
    __syncthreads();

    if (h == 0) {
        float z0 = fc2_b[0], zo1 = fc2_b[1];
        for (int j = 0; j < FC_DIM; ++j) {
            z0  += fc2_w[j] * z1[j];
            zo1 += fc2_w[FC_DIM + j] * z1[j];
        }
        const float m = fmaxf(z0, zo1);
        const float lse = m + logf(expf(z0 - m) + expf(zo1 - m));
        out[b * O_DIM + 0] = z0 - lse;
        out[b * O_DIM + 1] = zo1 - lse;
    }
}

extern "C" void kernel_launch(void* const* d_in, const int* in_sizes, int n_in,
                              void* d_out, int out_size, void* d_ws, size_t ws_size,
                              hipStream_t stream) {
    const float* x     = (const float*)d_in[0];
    const float* w_ig  = (const float*)d_in[1];
    const float* w_ii  = (const float*)d_in[2];
    const float* w_if  = (const float*)d_in[3];
    const float* w_io  = (const float*)d_in[4];
    // d_in[5..8] = w_hg/w_hi/w_hf/w_ho multiply a zero hidden state -> skipped
    const float* b_g   = (const float*)d_in[9];
    const float* b_i   = (const float*)d_in[10];
    const float* b_f   = (const float*)d_in[11];
    const float* b_o   = (const float*)d_in[12];
    const float* fc1_w = (const float*)d_in[13];
    const float* fc1_b = (const float*)d_in[14];
    const float* fc2_w = (const float*)d_in[15];
    const float* fc2_b = (const float*)d_in[16];

    // Workspace: wg/wi/wf bf16 (3 x 2 MB) + wsF/wsA (2 x 1 MB)
    const size_t NW = (size_t)B_DIM * H_DIM * I_DIM;    // 1,048,576
    short* wgc = (short*)d_ws;
    short* wic = wgc + NW;
    short* wfc = wic + NW;
    float* wsF = (float*)(wfc + NW);
    float* wsA = wsF + (size_t)B_DIM * NC * H_DIM;
    float* out = (float*)d_out;

    convert_w_kernel<<<dim3(NW / (256 * 8), 3), 256, 0, stream>>>(
        w_ig, w_ii, w_if, wgc, wic, wfc);

    // bid = chunk*64 + b (b-minor => per-b weight reuse within an XCD)
    gates_scan_kernel<<<dim3(B_DIM * NC), 512, 0, stream>>>(
        x, wgc, wic, wfc, b_g, b_i, b_f, wsF, wsA);

    finish_kernel<<<B_DIM, 128, 0, stream>>>(x, w_io, b_o, fc1_w, fc1_b,
                                             fc2_w, fc2_b, wsF, wsA, out);
}

// Round 6
// 162.295 us; speedup vs baseline: 1.6633x; 1.6633x over previous
//
#include <hip/hip_runtime.h>
#include <hip/hip_bf16.h>
#include <cstddef>

#define T_DIM 2048
#define B_DIM 64
#define I_DIM 128
#define H_DIM 128
#define FC_DIM 32
#define O_DIM 2

#define NC 32                // time chunks
#define TC (T_DIM / NC)      // 64 timesteps per chunk
#define MT 4                 // 4 m-tiles of 16 t per chunk
#define SUBT (TC / 4)        // 16 timesteps per quad sub-chunk
#define CPB 4                // chunks per block (double-buffered LDS)
#define NG (NC / CPB)        // 8 chunk-groups = grid.y

#define LOG2E  1.44269504088896f
#define LOG2E2 2.88539008177793f

typedef __attribute__((ext_vector_type(8))) short bf16x8;
typedef __attribute__((ext_vector_type(4))) float f32x4;

// packed fp32x8 -> bf16x8 (RNE) via v_cvt_pk_bf16_f32
__device__ __forceinline__ bf16x8 cvt8(const float* __restrict__ p) {
    union { bf16x8 v; __hip_bfloat162 h2[4]; } u;
#pragma unroll
    for (int j = 0; j < 4; ++j) {
        float2 f2 = {p[2 * j], p[2 * j + 1]};
        u.h2[j] = __float22bfloat162_rn(f2);
    }
    return u.v;
}

// Pass 0: gate weights fp32 -> bf16, pre-scaled by log2e factors so the
// gates kernel can use exp2 directly. Layout preserved [b][h][i].
__global__ void convert_w_kernel(const float* __restrict__ wg,
                                 const float* __restrict__ wi,
                                 const float* __restrict__ wf,
                                 short* __restrict__ og,
                                 short* __restrict__ oi,
                                 short* __restrict__ of)
{
    const float* src = (blockIdx.y == 0) ? wg : (blockIdx.y == 1) ? wi : wf;
    short* dst       = (blockIdx.y == 0) ? og : (blockIdx.y == 1) ? oi : of;
    const float scale = (blockIdx.y == 0) ? LOG2E2 : LOG2E;
    const size_t idx = ((size_t)blockIdx.x * 256 + threadIdx.x) * 8;
    float4 u0 = *(const float4*)(src + idx);
    float4 u1 = *(const float4*)(src + idx + 4);
    float a[8] = {u0.x * scale, u0.y * scale, u0.z * scale, u0.w * scale,
                  u1.x * scale, u1.y * scale, u1.z * scale, u1.w * scale};
    *(bf16x8*)(dst + idx) = cvt8(a);
}

// Pass 1: one block per (b, chunk-group of 4), 8 waves covering all 128 h.
// Double-buffered LDS: chunk i+1's x loads are issued one compute-phase
// ahead; convert into alternate buffer; 4 barriers per block.
// Per chunk: Phase A (2 waves per m-tile convert x -> bf16 A-frags in LDS),
// Phase B (per m-tile: 4 ds_read_b128, 12 MFMA, exp2 activations, per-quad
// affine scan), cross-quad combine, fold into running group affine.
// m-row -> t map within chunk: t(m) = (m>>2)*SUBT + mt*4 + (m&3); D rows
// (row = quad*4 + r) -> t = quad*SUBT + mt*4 + r.
__global__ __launch_bounds__(512, 4)
void gates_scan_kernel(const float* __restrict__ x,
    const short* __restrict__ wg, const short* __restrict__ wi,
    const short* __restrict__ wf,
    const float* __restrict__ b_g, const float* __restrict__ b_i,
    const float* __restrict__ b_f,
    float* __restrict__ wsF, float* __restrict__ wsA)
{
    // frag[buf][mt][kk][lane][8 shorts] = 2*4*4*64*8 shorts = 32 KB
    __shared__ short frag[2][MT * 4 * 64 * 8];

    const int L    = threadIdx.x & 63;
    const int wv   = threadIdx.x >> 6;   // 0..7
    const int col  = L & 15;
    const int quad = L >> 4;
    const int bid  = blockIdx.x;
    const int b   = bid & (B_DIM - 1);   // b-minor: same-b blocks together on XCD
    const int grp = bid >> 6;            // 0..7 -> chunks 4*grp .. 4*grp+3
    const int c0  = grp * CPB;

    // ---- weight fragments for this wave's 16 h columns: h = wv*16 + col
    const int h = wv * 16 + col;
    bf16x8 Bg[4], Bi[4], Bf[4];
    {
        const size_t wo = ((size_t)b * H_DIM + h) * I_DIM + quad * 8;
#pragma unroll
        for (int kk = 0; kk < 4; ++kk) {
            Bg[kk] = *(const bf16x8*)(wg + wo + kk * 32);
            Bi[kk] = *(const bf16x8*)(wi + wo + kk * 32);
            Bf[kk] = *(const bf16x8*)(wf + wo + kk * 32);
        }
    }
    const float biasg = b_g[b * H_DIM + h] * LOG2E2;
    const float biasi = b_i[b * H_DIM + h] * LOG2E;
    const float biasf = b_f[b * H_DIM + h] * LOG2E;

    // Phase-A role of this wave: m-tile mt = wv&3, k-slices (wv>>2)*2 + {0,1}
    const int amt = wv & 3;
    const int ak0 = (wv >> 2) * 2;
    const int atl = (col >> 2) * SUBT + amt * 4 + (col & 3);  // t within chunk
    // x pointer for chunk c: x + ((c*TC + atl)*B + b)*I + i0
    const float* xbase = x + ((size_t)atl * B_DIM + b) * I_DIM;

    float Fr = 1.0f, Ar = 0.0f;  // running group affine

    // prologue: load + convert chunk c0 into buf0; issue loads for c0+1
    float4 a0, a1, a2, a3;
    {
        const float* xp = xbase + (size_t)(c0 * TC) * (B_DIM * I_DIM);
        const int i0 = quad * 8 + ak0 * 32;
        a0 = *(const float4*)(xp + i0);
        a1 = *(const float4*)(xp + i0 + 4);
        a2 = *(const float4*)(xp + i0 + 32);
        a3 = *(const float4*)(xp + i0 + 36);
        float v0[8] = {a0.x, a0.y, a0.z, a0.w, a1.x, a1.y, a1.z, a1.w};
        float v1[8] = {a2.x, a2.y, a2.z, a2.w, a3.x, a3.y, a3.z, a3.w};
        *(bf16x8*)(&frag[0][(((amt * 4 + ak0) * 64) + L) * 8])     = cvt8(v0);
        *(bf16x8*)(&frag[0][(((amt * 4 + ak0 + 1) * 64) + L) * 8]) = cvt8(v1);
    }
    {   // prefetch chunk c0+1 (lands during first compute phase)
        const float* xp = xbase + (size_t)((c0 + 1) * TC) * (B_DIM * I_DIM);
        const int i0 = quad * 8 + ak0 * 32;
        a0 = *(const float4*)(xp + i0);
        a1 = *(const float4*)(xp + i0 + 4);
        a2 = *(const float4*)(xp + i0 + 32);
        a3 = *(const float4*)(xp + i0 + 36);
    }
    __syncthreads();  // buf0 complete

#pragma unroll
    for (int ci = 0; ci < CPB; ++ci) {
        const int cur = ci & 1;

        // ---- Phase B: compute chunk c0+ci from frag[cur]
        float Fq = 1.0f, Aq = 0.0f;
#pragma unroll
        for (int mt = 0; mt < MT; ++mt) {
            bf16x8 ah[4];
#pragma unroll
            for (int kk = 0; kk < 4; ++kk)
                ah[kk] = *(const bf16x8*)(&frag[cur][(((mt * 4 + kk) * 64) + L) * 8]);
            f32x4 accg = {0.f, 0.f, 0.f, 0.f};
            f32x4 acci = {0.f, 0.f, 0.f, 0.f};
            f32x4 accf = {0.f, 0.f, 0.f, 0.f};
#pragma unroll
            for (int kk = 0; kk < 4; ++kk) {
                accg = __builtin_amdgcn_mfma_f32_16x16x32_bf16(ah[kk], Bg[kk], accg, 0, 0, 0);
                acci = __builtin_amdgcn_mfma_f32_16x16x32_bf16(ah[kk], Bi[kk], acci, 0, 0, 0);
                accf = __builtin_amdgcn_mfma_f32_16x16x32_bf16(ah[kk], Bf[kk], accf, 0, 0, 0);
            }
#pragma unroll
            for (int r = 0; r < 4; ++r) {
                float g  = 2.0f * __builtin_amdgcn_rcpf(
                               1.0f + __builtin_amdgcn_exp2f(-(accg[r] + biasg))) - 1.0f;
                float iv = __builtin_amdgcn_rcpf(
                               1.0f + __builtin_amdgcn_exp2f(-(acci[r] + biasi)));
                float fv = __builtin_amdgcn_rcpf(
                               1.0f + __builtin_amdgcn_exp2f(-(accf[r] + biasf)));
                Aq = fv * Aq + iv * g;
                Fq = fv * Fq;
            }
        }
        // cross-quad ordered combine -> all lanes hold full-chunk affine
        float Fo = __shfl_xor(Fq, 16, 64);
        float Ao = __shfl_xor(Aq, 16, 64);
        if ((quad & 1) == 0) { Aq = Fo * Aq + Ao; Fq = Fo * Fq; }
        else                 { Aq = Fq * Ao + Aq; Fq = Fq * Fo; }
        Fo = __shfl_xor(Fq, 32, 64);
        Ao = __shfl_xor(Aq, 32, 64);
        if (quad < 2) { Aq = Fo * Aq + Ao; Fq = Fo * Fq; }
        else          { Aq = Fq * Ao + Aq; Fq = Fq * Fo; }
        // fold chunk (later in time) into running group affine
        Ar = Fq * Ar + Aq;
        Fr = Fq * Fr;

        if (ci < CPB - 1) {
            __syncthreads();  // all waves done reading frag[1-cur] (iter ci-1)
            // convert prefetched chunk c0+ci+1 into frag[1-cur]
            {
                float v0[8] = {a0.x, a0.y, a0.z, a0.w, a1.x, a1.y, a1.z, a1.w};
                float v1[8] = {a2.x, a2.y, a2.z, a2.w, a3.x, a3.y, a3.z, a3.w};
                *(bf16x8*)(&frag[1 - cur][(((amt * 4 + ak0) * 64) + L) * 8])     = cvt8(v0);
                *(bf16x8*)(&frag[1 - cur][(((amt * 4 + ak0 + 1) * 64) + L) * 8]) = cvt8(v1);
            }
            if (ci < CPB - 2) {  // prefetch chunk c0+ci+2
                const float* xp = xbase + (size_t)((c0 + ci + 2) * TC) * (B_DIM * I_DIM);
                const int i0 = quad * 8 + ak0 * 32;
                a0 = *(const float4*)(xp + i0);
                a1 = *(const float4*)(xp + i0 + 4);
                a2 = *(const float4*)(xp + i0 + 32);
                a3 = *(const float4*)(xp + i0 + 36);
            }
            __syncthreads();  // frag[1-cur] ready
        }
    }

    if (quad == 0) {
        const int idx = (b * NG + grp) * H_DIM + h;
        wsF[idx] = Fr;
        wsA[idx] = Ar;
    }
}

// Pass 2: fold NG group-affines -> c_fin; o-gate at t=T-1 (fp32 dot);
// h_fin = o*tanh(c); classifier + log_softmax. One block per batch.
__global__ void finish_kernel(const float* __restrict__ x,
    const float* __restrict__ w_io, const float* __restrict__ b_o,
    const float* __restrict__ fc1_w, const float* __restrict__ fc1_b,
    const float* __restrict__ fc2_w, const float* __restrict__ fc2_b,
    const float* __restrict__ wsF, const float* __restrict__ wsA,
    float* __restrict__ out)
{
    const int b = blockIdx.x;
    const int h = threadIdx.x;  // 128 threads
    __shared__ float hf[H_DIM];
    __shared__ float z1[FC_DIM];

    float c = 0.0f;
#pragma unroll
    for (int g = 0; g < NG; ++g) {
        const int idx = (b * NG + g) * H_DIM + h;
        c = wsF[idx] * c + wsA[idx];
    }
    const float* xl = x + ((size_t)(T_DIM - 1) * B_DIM + b) * I_DIM;
    const float* wo = w_io + ((size_t)b * H_DIM + h) * I_DIM;
    float acc = b_o[b * H_DIM + h];
#pragma unroll 8
    for (int i = 0; i < I_DIM; i += 4) {
        float4 xa = *(const float4*)(xl + i);
        float4 wa = *(const float4*)(wo + i);
        acc += xa.x * wa.x + xa.y * wa.y + xa.z * wa.z + xa.w * wa.w;
    }
    const float o = 1.0f / (1.0f + expf(-acc));
    hf[h] = o * tanhf(c);
    __syncthreads();

    if (h < FC_DIM) {
        float a = fc1_b[h];
        const float* w1 = fc1_w + h * H_DIM;
        for (int i = 0; i < H_DIM; ++i) a += w1[i] * hf[i];
        z1[h] = tanhf(a);
    }
    __syncthreads();

    if (h == 0) {
        float z0 = fc2_b[0], zo1 = fc2_b[1];
        for (int j = 0; j < FC_DIM; ++j) {
            z0  += fc2_w[j] * z1[j];
            zo1 += fc2_w[FC_DIM + j] * z1[j];
        }
        const float m = fmaxf(z0, zo1);
        const float lse = m + logf(expf(z0 - m) + expf(zo1 - m));
        out[b * O_DIM + 0] = z0 - lse;
        out[b * O_DIM + 1] = zo1 - lse;
    }
}

extern "C" void kernel_launch(void* const* d_in, const int* in_sizes, int n_in,
                              void* d_out, int out_size, void* d_ws, size_t ws_size,
                              hipStream_t stream) {
    const float* x     = (const float*)d_in[0];
    const float* w_ig  = (const float*)d_in[1];
    const float* w_ii  = (const float*)d_in[2];
    const float* w_if  = (const float*)d_in[3];
    const float* w_io  = (const float*)d_in[4];
    // d_in[5..8] = w_hg/w_hi/w_hf/w_ho multiply a zero hidden state -> skipped
    const float* b_g   = (const float*)d_in[9];
    const float* b_i   = (const float*)d_in[10];
    const float* b_f   = (const float*)d_in[11];
    const float* b_o   = (const float*)d_in[12];
    const float* fc1_w = (const float*)d_in[13];
    const float* fc1_b = (const float*)d_in[14];
    const float* fc2_w = (const float*)d_in[15];
    const float* fc2_b = (const float*)d_in[16];

    // Workspace: wg/wi/wf bf16 (3 x 2 MB) + wsF/wsA (2 x 256 KB)
    const size_t NW = (size_t)B_DIM * H_DIM * I_DIM;    // 1,048,576
    short* wgc = (short*)d_ws;
    short* wic = wgc + NW;
    short* wfc = wic + NW;
    float* wsF = (float*)(wfc + NW);
    float* wsA = wsF + (size_t)B_DIM * NG * H_DIM;
    float* out = (float*)d_out;

    convert_w_kernel<<<dim3(NW / (256 * 8), 3), 256, 0, stream>>>(
        w_ig, w_ii, w_if, wgc, wic, wfc);

    // bid = grp*64 + b; 512 blocks = exactly 2 resident blocks per CU
    gates_scan_kernel<<<dim3(B_DIM * NG), 512, 0, stream>>>(
        x, wgc, wic, wfc, b_g, b_i, b_f, wsF, wsA);

    finish_kernel<<<B_DIM, 128, 0, stream>>>(x, w_io, b_o, fc1_w, fc1_b,
                                             fc2_w, fc2_b, wsF, wsA, out);
}